// Round 16
// baseline (99.937 us; speedup 1.0000x reference)
//
#include <hip/hip_runtime.h>
#include <math.h>

#define B_   64
#define L_   500
#define F_   256
#define H_   4
#define DK   64
#define LOG2E 1.44269504088896340736f

typedef unsigned short u16;
typedef unsigned int   u32;
typedef __attribute__((ext_vector_type(8))) short short8;
typedef __attribute__((ext_vector_type(4))) float f32x4;

static __device__ __forceinline__ u16 f2bf(float f) {
    u32 u = __float_as_uint(f);
    u32 r = (u + 0x7FFFu + ((u >> 16) & 1u)) >> 16;
    return (u16)r;
}
// pack two floats to 2x bf16 (round-half-up) in one u32: {hi=y, lo=x}
static __device__ __forceinline__ u32 pk_bf16_up(float x, float y) {
    u32 xb = __float_as_uint(x) + 0x8000u;
    u32 yb = __float_as_uint(y) + 0x8000u;
    return (xb >> 16) | (yb & 0xFFFF0000u);
}
static __device__ __forceinline__ float exp2_fast(float x) {
#if __has_builtin(__builtin_amdgcn_exp2f)
    return __builtin_amdgcn_exp2f(x);
#else
    return exp2f(x);
#endif
}

typedef __attribute__((address_space(3))) u32 lds32;
typedef const __attribute__((address_space(1))) u32 gbl32;
// async global->LDS DMA, 16 B/lane, LDS dest = uniform base + lane*16
static __device__ __forceinline__ void gload_lds16(const u16* g, u16* l) {
    __builtin_amdgcn_global_load_lds((gbl32*)g, (lds32*)l, 16, 0, 0);
}

// ---------------------------------------------------------------------------
// Prep: bf16 transposed weights + padded b2 + pad-zeroing of ws regions.
//  fcwT [256][256] ([n][k]); w1T[64][64]
//  wqf/wvf: MFMA-B-FRAGMENT layout for proj (L2-resident, coalesced reads):
//        flat i (16 bits): j=i&7, ln=(i>>3)&63, tn=(i>>9)&15, ks=(i>>13)&1,
//        kc=i>>14 (2 bits).  k = kc*64+ks*32+(ln>>4)*8+j ; n = tn*16+(ln&15)
//        wqf[i] = bf16(wq[k*256+n]).  Full 65536-entry table.
//  w2sw: chunk-tiled + XOR-swizzled + PRE-SCALED by log2(e)
//  b2p[512] float = log2e * b2 (tail -1e30 -> exp2() == 0)
// ---------------------------------------------------------------------------
__global__ __launch_bounds__(256) void prep_kernel(
    const float* __restrict__ wq, const float* __restrict__ wv,
    const float* __restrict__ fcw, const float* __restrict__ w1,
    const float* __restrict__ w2, const float* __restrict__ b2,
    u16* __restrict__ wqf, u16* __restrict__ wvf, u16* __restrict__ fcwT,
    u16* __restrict__ w1T, u16* __restrict__ w2sw,
    u16* __restrict__ qh_bf, u16* __restrict__ vhT, float* __restrict__ b2p)
{
    int t = blockIdx.x * 256 + threadIdx.x;
    int stride = gridDim.x * 256;                 // 16384
    // fcw: plain [n][k] transpose (final_kernel's padded-LDS path)
    for (int i = t; i < 256 * 256; i += stride) {
        int n = i >> 8, k = i & 255;
        fcwT[i] = f2bf(fcw[k * 256 + n]);
    }
    // wq/wv: MFMA B-fragment layout for proj's direct-from-L2 reads
    for (int i = t; i < 65536; i += stride) {
        int j  = i & 7;
        int ln = (i >> 3) & 63;
        int tn = (i >> 9) & 15;
        int ks = (i >> 13) & 1;
        int kc = i >> 14;
        int k  = kc * 64 + ks * 32 + (ln >> 4) * 8 + j;
        int n  = tn * 16 + (ln & 15);
        wqf[i] = f2bf(wq[k * 256 + n]);
        wvf[i] = f2bf(wv[k * 256 + n]);
    }
    for (int i = t; i < 64 * 64; i += stride) {
        int n = i >> 6, k = i & 63;
        w1T[i] = f2bf(w1[k * 64 + n]);
    }
    // w2 chunk-tiled + swizzled + log2e-scaled
    for (int i = t; i < 512 * 64; i += stride) {
        int cc  = i >> 12;
        int row = (i >> 6) & 63;
        int kc  = i & 63;
        int n   = cc * 64 + row;
        int kl  = kc ^ ((row & 7) << 3);
        w2sw[i] = f2bf((n < 500 ? w2[kl * 500 + n] : 0.f) * LOG2E);
    }
    // padded, scaled bias (tail -> exp2() == 0)
    for (int i = t; i < 512; i += stride)
        b2p[i] = (i < 500) ? b2[i] * LOG2E : -1e30f;
    // zero qh_bf pad rows read by attn (rows >= 128000); b2p lives at 8195072+
    for (int i = t; i < 3072; i += stride)
        qh_bf[8192000 + i] = 0;
    // zero vhT swizzled pad slots: chunk 7, k 52..63 for every (bh, d)
    for (int i = t; i < 196608; i += stride) {
        int bh = i / 768;
        int r  = i - bh * 768;
        int d  = r / 12;
        int kk = 52 + (r - d * 12);
        vhT[((size_t)((bh * 8 + 7) * 64 + d)) * 64 + (kk ^ ((d & 7) << 3))] = 0;
    }
}

// ---------------------------------------------------------------------------
// Kernel 1: head projections — barrier-free, LDS-free, wave-private tiles.
// grid (1000), block 256 = 4 waves; wave-tile t = bid*4+wv (0..3999):
// t<2000 -> q rows [t*16, t*16+16); t>=2000 -> v rows ((t-2000)*16..).
// Wave loads its 16 rows of X via 16 independent float4 HBM loads (16x128B
// contiguous segments), packs ALL 8 A-fragments into 32 VGPR, then loops 16
// output col-tiles: 8 coalesced W-fragment loads from the L2-resident
// wqf/wvf table -> 8 chained MFMAs -> store immediately (one 4-VGPR acc
// live).  Zero __syncthreads, zero LDS: waves self-pace, 16+ outstanding
// loads each — the mechanism the barrier-chunked variants (all stuck at
// ~40us with 900cy-latency/130cy-compute chunks) lacked.
// __launch_bounds__(256,4): 128-VGPR budget, live ~90 -> no spill.
// ---------------------------------------------------------------------------
__global__ __launch_bounds__(256, 4) void proj_kernel(
    const float* __restrict__ q, const float* __restrict__ v,
    const u16* __restrict__ wqf, const u16* __restrict__ wvf,
    u16* __restrict__ qh_bf, u16* __restrict__ vhT)
{
    const int tid  = threadIdx.x;
    const int wv   = tid >> 6, ln = tid & 63;
    const int n16  = ln & 15, quad = ln >> 4;
    const int t    = blockIdx.x * 4 + wv;        // 0..3999 (which uniform/block)
    const int which = (t >= 2000) ? 1 : 0;
    const int r0   = (t - 2000 * which) * 16;
    const float* __restrict__ x  = which ? v : q;
    const u16*   __restrict__ wf = which ? wvf : wqf;

    // ---- load this wave's 16 rows of X into A-fragments (32 VGPR) ----
    short8 af[8];
    {
        const float* xrow = x + (size_t)(r0 + n16) * 256 + quad * 8;
        #pragma unroll
        for (int kq = 0; kq < 8; kq++) {
            float4 xa = *(const float4*)(xrow + kq * 32);
            float4 xb = *(const float4*)(xrow + kq * 32 + 4);
            union { short8 s; u32 u[4]; } tc;
            tc.u[0] = pk_bf16_up(xa.x, xa.y);
            tc.u[1] = pk_bf16_up(xa.z, xa.w);
            tc.u[2] = pk_bf16_up(xb.x, xb.y);
            tc.u[3] = pk_bf16_up(xb.z, xb.w);
            af[kq] = tc.s;
        }
    }

    if (which == 0) {
        // qh_bf[((b*4+h)*500+l0)*64 + d]; per-i row bases precomputed
        size_t base_i[4];
        #pragma unroll
        for (int i = 0; i < 4; i++) {
            int m  = r0 + quad * 4 + i;
            int b  = m / 500;
            int l0 = m - 500 * b;
            base_i[i] = (size_t)(b * 2000 + l0) * 64 + n16;
        }
        #pragma unroll
        for (int tn = 0; tn < 16; tn++) {
            f32x4 c = {0.f, 0.f, 0.f, 0.f};
            #pragma unroll
            for (int kq = 0; kq < 8; kq++) {
                short8 bfr = *(const short8*)&wf[(((kq * 16 + tn) * 64) + ln) * 8];
                c = __builtin_amdgcn_mfma_f32_16x16x32_bf16(af[kq], bfr, c, 0, 0, 0);
            }
            size_t hoff = (size_t)(tn >> 2) * 32000 + (tn & 3) * 16;
            #pragma unroll
            for (int i = 0; i < 4; i++)
                qh_bf[base_i[i] + hoff] = f2bf(c[i]);
        }
    } else {
        // vhT[((b*4+h)*8+vc)*4096 + d*64 + (kk^((d&7)<<3))], kk%4==0 ->
        // 4 consecutive u16 (rows i=0..3) stored as one uint2
        int m0  = r0 + quad * 4;                 // 4-aligned; never straddles b
        int b   = m0 / 500;
        int l00 = m0 - 500 * b;
        int vc  = l00 >> 6, kk = l00 & 63;
        size_t base = (size_t)b * 131072 + (size_t)vc * 4096;
        #pragma unroll
        for (int tn = 0; tn < 16; tn++) {
            f32x4 c = {0.f, 0.f, 0.f, 0.f};
            #pragma unroll
            for (int kq = 0; kq < 8; kq++) {
                short8 bfr = *(const short8*)&wf[(((kq * 16 + tn) * 64) + ln) * 8];
                c = __builtin_amdgcn_mfma_f32_16x16x32_bf16(af[kq], bfr, c, 0, 0, 0);
            }
            int d = (tn & 3) * 16 + n16;
            __align__(8) u16 t4[4];
            #pragma unroll
            for (int i = 0; i < 4; i++) t4[i] = f2bf(c[i]);
            *(uint2*)&vhT[base + (size_t)(tn >> 2) * 32768 + d * 64 +
                          (kk ^ ((d & 7) << 3))] = *(const uint2*)t4;
        }
    }
}

// ---------------------------------------------------------------------------
// Kernel 2: dense-synthesizer attention — LDS-bandwidth-optimized, 1 pass.
// grid (256) = 1 block/bh/CU; block 512 = 8 waves x 64 rows (4 rgs of 16).
// B-fragments (w2, V, bias) feed FOUR MFMAs per read; 8 chunk-steps total.
// LDS: w2 64KB + V dbuf 16KB + b2 2KB + scr 72KB = 157.7KB (1 block/CU).
// ---------------------------------------------------------------------------
__global__ __launch_bounds__(512, 1) void attn_kernel(
    const u16* __restrict__ qh, const u16* __restrict__ vhT,
    const u16* __restrict__ w1T, const float* __restrict__ b1,
    const u16* __restrict__ w2sw, const float* __restrict__ b2p,
    u16* __restrict__ ctx)
{
    __shared__ __align__(16) u16 w2all[32768];       // [cc][row][k^swz], 64KB
    __shared__ __align__(16) u16 v_s[2][4096];       // [buf][d*64 + k^swz], 16KB
    __shared__ __align__(16) float b2s[512];         // scaled bias, 2KB
    __shared__ __align__(16) u16 scr[8][4][16][72];  // per-wave/rg s,P scratch

    const int tid  = threadIdx.x;
    const int wv   = tid >> 6;       // 0..7
    const int ln   = tid & 63;
    const int n16  = ln & 15;
    const int quad = ln >> 4;
    const int bh   = blockIdx.x;
    const int r0   = wv * 64;        // wave's 64 rows

    const u16* vg = vhT + (size_t)bh * 32768;

    // ---- one-shot staging: all of w2 (8 DMA/wave), v[0], b2 ----
    {
        int base = wv * 4096;
        #pragma unroll
        for (int j = 0; j < 8; j++)
            gload_lds16(w2sw + base + j * 512 + ln * 8, &w2all[base + j * 512]);
        gload_lds16(vg + wv * 512 + ln * 8, &v_s[0][wv * 512]);
        if (wv < 2)
            gload_lds16((const u16*)b2p + wv * 512 + ln * 8, (u16*)&b2s[wv * 256]);
    }

    const int b = bh >> 2, h = bh & 3;

    // ---- Phase A (swapped): s = relu(qh @ w1 + b1) -> packed scr, 4 rgs ----
    {
        short8 a0[4], a1[4];
        #pragma unroll
        for (int rg = 0; rg < 4; rg++) {
            const u16* qbase =
                qh + ((size_t)(bh * 500 + r0 + rg * 16 + n16)) * 64;
            a0[rg] = *(const short8*)(qbase + quad * 8);
            a1[rg] = *(const short8*)(qbase + 32 + quad * 8);
        }
        #pragma unroll
        for (int nt = 0; nt < 4; nt++) {
            const u16* wb = w1T + (nt * 16 + n16) * 64;
            short8 wA0 = *(const short8*)(wb + quad * 8);
            short8 wA1 = *(const short8*)(wb + 32 + quad * 8);
            float4 bv = *(const float4*)&b1[nt * 16 + quad * 4];
            #pragma unroll
            for (int rg = 0; rg < 4; rg++) {
                f32x4 c = {bv.x, bv.y, bv.z, bv.w};
                c = __builtin_amdgcn_mfma_f32_16x16x32_bf16(wA0, a0[rg], c, 0, 0, 0);
                c = __builtin_amdgcn_mfma_f32_16x16x32_bf16(wA1, a1[rg], c, 0, 0, 0);
                u32 p01 = pk_bf16_up(fmaxf(c[0], 0.f), fmaxf(c[1], 0.f));
                u32 p23 = pk_bf16_up(fmaxf(c[2], 0.f), fmaxf(c[3], 0.f));
                *(uint2*)&scr[wv][rg][n16][nt * 16 + quad * 4] =
                    make_uint2(p01, p23);
            }
        }
    }
    short8 sa0[4], sa1[4];
    #pragma unroll
    for (int rg = 0; rg < 4; rg++) {
        sa0[rg] = *(const short8*)&scr[wv][rg][n16][quad * 8];
        sa1[rg] = *(const short8*)&scr[wv][rg][n16][32 + quad * 8];
    }

    f32x4 oacc[4][4];
    #pragma unroll
    for (int rg = 0; rg < 4; rg++)
        #pragma unroll
        for (int nt = 0; nt < 4; nt++)
            oacc[rg][nt] = (f32x4){0.f, 0.f, 0.f, 0.f};
    float sm[4] = {0.f, 0.f, 0.f, 0.f};

    __syncthreads();   // prologue staging complete

    // ---- main: 8 chunks; B-frags shared across 4 rgs ----
    #pragma unroll 2
    for (int cc = 0; cc < 8; cc++) {
        if (cc < 7)
            gload_lds16(vg + (cc + 1) * 4096 + wv * 512 + ln * 8,
                        &v_s[(cc + 1) & 1][wv * 512]);
        const u16* vbuf = &v_s[cc & 1][0];

        // logits (swapped) + exp2 + pack -> scr, per t-tile
        #pragma unroll
        for (int t = 0; t < 4; t++) {
            int r  = t * 16 + n16;
            int sw = (r & 7) << 3;
            const u16* wb = &w2all[cc * 4096 + r * 64];
            short8 wA0 = *(const short8*)&wb[(quad * 8) ^ sw];
            short8 wA1 = *(const short8*)&wb[(32 + quad * 8) ^ sw];
            float4 bv = *(const float4*)&b2s[cc * 64 + t * 16 + quad * 4];
            #pragma unroll
            for (int rg = 0; rg < 4; rg++) {
                f32x4 c = {bv.x, bv.y, bv.z, bv.w};
                c = __builtin_amdgcn_mfma_f32_16x16x32_bf16(wA0, sa0[rg], c, 0, 0, 0);
                c = __builtin_amdgcn_mfma_f32_16x16x32_bf16(wA1, sa1[rg], c, 0, 0, 0);
                float e0 = exp2_fast(c[0]);
                float e1 = exp2_fast(c[1]);
                float e2 = exp2_fast(c[2]);
                float e3 = exp2_fast(c[3]);
                sm[rg] += (e0 + e1) + (e2 + e3);
                *(uint2*)&scr[wv][rg][n16][t * 16 + quad * 4] =
                    make_uint2(pk_bf16_up(e0, e1), pk_bf16_up(e2, e3));
            }
        }
        // PV: V-frag read once, feeds all 4 rgs
        #pragma unroll
        for (int ks = 0; ks < 2; ks++) {
            short8 pa[4];
            #pragma unroll
            for (int rg = 0; rg < 4; rg++)
                pa[rg] = *(const short8*)&scr[wv][rg][n16][ks * 32 + quad * 8];
            #pragma unroll
            for (int nt = 0; nt < 4; nt++) {
                int d   = nt * 16 + n16;
                int swd = (d & 7) << 3;
                short8 vb = *(const short8*)&vbuf[d * 64 +
                                                  ((ks * 32 + quad * 8) ^ swd)];
                #pragma unroll
                for (int rg = 0; rg < 4; rg++)
                    oacc[rg][nt] = __builtin_amdgcn_mfma_f32_16x16x32_bf16(
                        pa[rg], vb, oacc[rg][nt], 0, 0, 0);
            }
        }
        __syncthreads();   // next V staged; buffer safe to flip
    }

    // ---- epilogue: row-sum reduce + scaled bf16 store ----
    #pragma unroll
    for (int rg = 0; rg < 4; rg++) {
        float smt = sm[rg];
        smt += __shfl_xor(smt, 16);
        smt += __shfl_xor(smt, 32);   // lane now holds total for row n16
        #pragma unroll
        for (int i = 0; i < 4; i++) {
            int lrow = r0 + rg * 16 + quad * 4 + i;
            float si = __shfl(smt, quad * 4 + i);   // row (quad*4+i)'s sum
            if (lrow < 500) {
                float s = 1.f / si;
                u16* dst = &ctx[((size_t)(b * 500 + lrow)) * 256 + h * 64];
                #pragma unroll
                for (int nt = 0; nt < 4; nt++)
                    dst[nt * 16 + n16] = f2bf(oacc[rg][nt][i] * s);
            }
        }
    }
}

// ---------------------------------------------------------------------------
// Kernel 3: out = LayerNorm(ctx @ fc_w + q), bf16 MFMA + fused LN epilogue.
// grid (500), block 512 = 8 waves in 2x4; block tile 64 rows x 256 cols.
// ---------------------------------------------------------------------------
__global__ __launch_bounds__(512) void final_kernel(
    const u16* __restrict__ ctx, const u16* __restrict__ fcwT,
    const float* __restrict__ qres, const float* __restrict__ g,
    const float* __restrict__ bta, float* __restrict__ out)
{
    __shared__ u16 Xs[64][72];
    __shared__ u16 Ws[256][72];
    __shared__ float red[4][2][64];   // [wc][s1|s2][row]
    __shared__ float murs[2][64];     // [mu|rs][row]

    const int tid  = threadIdx.x;
    const int wvid = tid >> 6, ln = tid & 63;
    const int n16  = ln & 15, quad = ln >> 4;
    const int wr   = wvid >> 2, wc = wvid & 3;   // 2 x 4
    const int row0 = blockIdx.x * 64;

    f32x4 acc[2][4];
    #pragma unroll
    for (int mt = 0; mt < 2; mt++)
        #pragma unroll
        for (int nt = 0; nt < 4; nt++) acc[mt][nt] = (f32x4){0.f, 0.f, 0.f, 0.f};

    for (int kc = 0; kc < 256; kc += 64) {
        // stage X: 64 x 64 bf16
        {
            int idx = tid;
            int m = idx >> 3, k8 = idx & 7;
            *(uint4*)&Xs[m][k8 * 8] =
                *(const uint4*)&ctx[(size_t)(row0 + m) * 256 + kc + k8 * 8];
        }
        // stage W^T: 256 x 64 bf16
        #pragma unroll
        for (int j = 0; j < 4; j++) {
            int idx = tid + 512 * j;
            int n = idx >> 3, k8 = idx & 7;
            *(uint4*)&Ws[n][k8 * 8] = *(const uint4*)&fcwT[n * 256 + kc + k8 * 8];
        }
        __syncthreads();
        #pragma unroll
        for (int ks = 0; ks < 2; ks++) {
            short8 af[2], bfr[4];
            #pragma unroll
            for (int mt = 0; mt < 2; mt++)
                af[mt] = *(const short8*)&Xs[wr * 32 + mt * 16 + n16][ks * 32 + quad * 8];
            #pragma unroll
            for (int nt = 0; nt < 4; nt++)
                bfr[nt] = *(const short8*)&Ws[wc * 64 + nt * 16 + n16][ks * 32 + quad * 8];
            #pragma unroll
            for (int mt = 0; mt < 2; mt++)
                #pragma unroll
                for (int nt = 0; nt < 4; nt++)
                    acc[mt][nt] = __builtin_amdgcn_mfma_f32_16x16x32_bf16(
                        af[mt], bfr[nt], acc[mt][nt], 0, 0, 0);
        }
        __syncthreads();
    }

    // residual add
    #pragma unroll
    for (int mt = 0; mt < 2; mt++) {
        int m0 = row0 + wr * 32 + mt * 16 + quad * 4;
        #pragma unroll
        for (int i = 0; i < 4; i++) {
            const float* rp = &qres[(size_t)(m0 + i) * 256 + wc * 64 + n16];
            #pragma unroll
            for (int nt = 0; nt < 4; nt++)
                acc[mt][nt][i] += rp[nt * 16];
        }
    }
    // per-row partial sums -> LDS
    #pragma unroll
    for (int mt = 0; mt < 2; mt++) {
        #pragma unroll
        for (int i = 0; i < 4; i++) {
            float s1 = 0.f, s2 = 0.f;
            #pragma unroll
            for (int nt = 0; nt < 4; nt++) {
                float vv = acc[mt][nt][i];
                s1 += vv; s2 += vv * vv;
            }
            #pragma unroll
            for (int off = 1; off < 16; off <<= 1) {
                s1 += __shfl_xor(s1, off);
                s2 += __shfl_xor(s2, off);
            }
            if (n16 == 0) {
                int r = wr * 32 + mt * 16 + quad * 4 + i;
                red[wc][0][r] = s1;
                red[wc][1][r] = s2;
            }
        }
    }
    __syncthreads();
    if (tid < 64) {
        float S1 = red[0][0][tid] + red[1][0][tid] + red[2][0][tid] + red[3][0][tid];
        float S2 = red[0][1][tid] + red[1][1][tid] + red[2][1][tid] + red[3][1][tid];
        float mu  = S1 * 0.00390625f;
        float var = S2 * 0.00390625f - mu * mu;
        murs[0][tid] = mu;
        murs[1][tid] = rsqrtf(var + 1e-6f);
    }
    __syncthreads();

    float gv[4], bv[4];
    #pragma unroll
    for (int nt = 0; nt < 4; nt++) {
        int col = wc * 64 + nt * 16 + n16;
        gv[nt] = g[col];
        bv[nt] = bta[col];
    }
    #pragma unroll
    for (int mt = 0; mt < 2; mt++) {
        int rb = wr * 32 + mt * 16 + quad * 4;
        #pragma unroll
        for (int i = 0; i < 4; i++) {
            float mu = murs[0][rb + i];
            float rs = murs[1][rb + i];
            float* op = &out[(size_t)(row0 + rb + i) * 256 + wc * 64 + n16];
            #pragma unroll
            for (int nt = 0; nt < 4; nt++)
                op[nt * 16] = (acc[mt][nt][i] - mu) * rs * gv[nt] + bv[nt];
        }
    }
}

// ---------------------------------------------------------------------------
extern "C" void kernel_launch(void* const* d_in, const int* in_sizes, int n_in,
                              void* d_out, int out_size, void* d_ws, size_t ws_size,
                              hipStream_t stream)
{
    const float* q   = (const float*)d_in[0];
    const float* v   = (const float*)d_in[2];
    const float* wqs = (const float*)d_in[3];
    const float* wvs = (const float*)d_in[4];
    const float* w1  = (const float*)d_in[5];
    const float* b1  = (const float*)d_in[6];
    const float* w2  = (const float*)d_in[7];
    const float* b2  = (const float*)d_in[8];
    const float* fcw = (const float*)d_in[9];
    const float* lng = (const float*)d_in[10];
    const float* lnb = (const float*)d_in[11];
    float* out = (float*)d_out;

    u16* qh_bf = (u16*)d_ws;            // 8,200,192 (rows >=500*256 are pad)
    u16* vhT   = qh_bf + 8200192;       // 8,388,608 (chunk-tiled + swizzled)
    u16* w1T   = vhT + 8388608;         // 4,096
    u16* w2sw  = w1T + 4096;            // 32,768 (chunk-tiled + swizzled + log2e)
    u16* wqf   = w2sw + 32768;          // 65,536 (MFMA-fragment layout)
    u16* wvf   = wqf + 65536;           // 65,536 (MFMA-fragment layout)
    u16* fcwT  = wvf + 65536;           // 65,536
    u16* ctx   = fcwT + 65536;          // 8,192,000
    float* b2p = (float*)(qh_bf + 8195072);  // 512 floats inside qh_bf tail pad

    prep_kernel <<<dim3(64),     256, 0, stream>>>(wqs, wvs, fcw, w1, w2, b2,
                                                   wqf, wvf, fcwT, w1T, w2sw,
                                                   qh_bf, vhT, b2p);
    proj_kernel <<<dim3(1000),   256, 0, stream>>>(q, v, wqf, wvf, qh_bf, vhT);
    attn_kernel <<<dim3(256),    512, 0, stream>>>(qh_bf, vhT, w1T, b1, w2sw, b2p, ctx);
    final_kernel<<<dim3(500),    512, 0, stream>>>(ctx, fcwT, q, lng, lnb, out);
}

// Round 17
// 90.198 us; speedup vs baseline: 1.1080x; 1.1080x over previous
//
#include <hip/hip_runtime.h>
#include <math.h>

#define B_   64
#define L_   500
#define F_   256
#define H_   4
#define DK   64
#define LOG2E 1.44269504088896340736f

typedef unsigned short u16;
typedef unsigned int   u32;
typedef __attribute__((ext_vector_type(8))) short short8;
typedef __attribute__((ext_vector_type(4))) float f32x4;

static __device__ __forceinline__ u16 f2bf(float f) {
    u32 u = __float_as_uint(f);
    u32 r = (u + 0x7FFFu + ((u >> 16) & 1u)) >> 16;
    return (u16)r;
}
// pack two floats to 2x bf16 (round-half-up) in one u32: {hi=y, lo=x}
static __device__ __forceinline__ u32 pk_bf16_up(float x, float y) {
    u32 xb = __float_as_uint(x) + 0x8000u;
    u32 yb = __float_as_uint(y) + 0x8000u;
    return (xb >> 16) | (yb & 0xFFFF0000u);
}
static __device__ __forceinline__ float exp2_fast(float x) {
#if __has_builtin(__builtin_amdgcn_exp2f)
    return __builtin_amdgcn_exp2f(x);
#else
    return exp2f(x);
#endif
}

typedef __attribute__((address_space(3))) u32 lds32;
typedef const __attribute__((address_space(1))) u32 gbl32;
// async global->LDS DMA, 16 B/lane, LDS dest = uniform base + lane*16
static __device__ __forceinline__ void gload_lds16(const u16* g, u16* l) {
    __builtin_amdgcn_global_load_lds((gbl32*)g, (lds32*)l, 16, 0, 0);
}

// ---------------------------------------------------------------------------
// Prep: bf16 transposed weights + padded b2 + pad-zeroing of ws regions.
//  fcwT [256][256] ([n][k]); w1T[64][64]
//  wqf/wvf: MFMA-B-FRAGMENT layout for proj (L2-resident, coalesced reads):
//        flat i (16 bits): j=i&7, ln=(i>>3)&63, tn=(i>>9)&15, ks=(i>>13)&1,
//        kc=i>>14 (2 bits).  k = kc*64+ks*32+(ln>>4)*8+j ; n = tn*16+(ln&15)
//        wqf[i] = bf16(wq[k*256+n]).  Full 65536-entry table.
//  w2sw: chunk-tiled + XOR-swizzled + PRE-SCALED by log2(e)
//  b2p[512] float = log2e * b2 (tail -1e30 -> exp2() == 0)
// ---------------------------------------------------------------------------
__global__ __launch_bounds__(256) void prep_kernel(
    const float* __restrict__ wq, const float* __restrict__ wv,
    const float* __restrict__ fcw, const float* __restrict__ w1,
    const float* __restrict__ w2, const float* __restrict__ b2,
    u16* __restrict__ wqf, u16* __restrict__ wvf, u16* __restrict__ fcwT,
    u16* __restrict__ w1T, u16* __restrict__ w2sw,
    u16* __restrict__ qh_bf, u16* __restrict__ vhT, float* __restrict__ b2p)
{
    int t = blockIdx.x * 256 + threadIdx.x;
    int stride = gridDim.x * 256;                 // 16384
    // fcw: plain [n][k] transpose (final_kernel's padded-LDS path)
    for (int i = t; i < 256 * 256; i += stride) {
        int n = i >> 8, k = i & 255;
        fcwT[i] = f2bf(fcw[k * 256 + n]);
    }
    // wq/wv: MFMA B-fragment layout for proj's direct-from-L2 reads
    for (int i = t; i < 65536; i += stride) {
        int j  = i & 7;
        int ln = (i >> 3) & 63;
        int tn = (i >> 9) & 15;
        int ks = (i >> 13) & 1;
        int kc = i >> 14;
        int k  = kc * 64 + ks * 32 + (ln >> 4) * 8 + j;
        int n  = tn * 16 + (ln & 15);
        wqf[i] = f2bf(wq[k * 256 + n]);
        wvf[i] = f2bf(wv[k * 256 + n]);
    }
    for (int i = t; i < 64 * 64; i += stride) {
        int n = i >> 6, k = i & 63;
        w1T[i] = f2bf(w1[k * 64 + n]);
    }
    // w2 chunk-tiled + swizzled + log2e-scaled
    for (int i = t; i < 512 * 64; i += stride) {
        int cc  = i >> 12;
        int row = (i >> 6) & 63;
        int kc  = i & 63;
        int n   = cc * 64 + row;
        int kl  = kc ^ ((row & 7) << 3);
        w2sw[i] = f2bf((n < 500 ? w2[kl * 500 + n] : 0.f) * LOG2E);
    }
    // padded, scaled bias (tail -> exp2() == 0)
    for (int i = t; i < 512; i += stride)
        b2p[i] = (i < 500) ? b2[i] * LOG2E : -1e30f;
    // zero qh_bf pad rows read by attn (rows >= 128000); b2p lives at 8195072+
    for (int i = t; i < 3072; i += stride)
        qh_bf[8192000 + i] = 0;
    // zero vhT swizzled pad slots: chunk 7, k 52..63 for every (bh, d)
    for (int i = t; i < 196608; i += stride) {
        int bh = i / 768;
        int r  = i - bh * 768;
        int d  = r / 12;
        int kk = 52 + (r - d * 12);
        vhT[((size_t)((bh * 8 + 7) * 64 + d)) * 64 + (kk ^ ((d & 7) << 3))] = 0;
    }
}

// ---------------------------------------------------------------------------
// Kernel 1: head projections — barrier-free, LDS-free, SOFTWARE-PIPELINED.
// grid (1000), block 256 = 4 waves; wave-tile t = bid*4+wv (0..3999).
// R16's serial tn-loop exposed ~400cy of L2 latency per tile (VGPR=44 ->
// compiler refused to pipeline).  Fix: manual 1-tile-ahead ping-pong with
// STATICALLY NAMED buffers bA/bB (rule-#20-safe) — while tile 2t computes
// from bA, tile 2t+1's 8 fragment loads are already in flight into bB.
// VGPR ~110 (af 32 + bA 32 + bB 32 + acc/addr) fits (256,4)'s 128 budget.
// ---------------------------------------------------------------------------
__global__ __launch_bounds__(256, 4) void proj_kernel(
    const float* __restrict__ q, const float* __restrict__ v,
    const u16* __restrict__ wqf, const u16* __restrict__ wvf,
    u16* __restrict__ qh_bf, u16* __restrict__ vhT)
{
    const int tid  = threadIdx.x;
    const int wv   = tid >> 6, ln = tid & 63;
    const int n16  = ln & 15, quad = ln >> 4;
    const int t    = blockIdx.x * 4 + wv;        // 0..3999 (uniform per wave)
    const int which = (t >= 2000) ? 1 : 0;
    const int r0   = (t - 2000 * which) * 16;
    const float* __restrict__ x  = which ? v : q;
    const u16*   __restrict__ wf = which ? wvf : wqf;

    // ---- load this wave's 16 rows of X into A-fragments (32 VGPR) ----
    short8 af[8];
    {
        const float* xrow = x + (size_t)(r0 + n16) * 256 + quad * 8;
        #pragma unroll
        for (int kq = 0; kq < 8; kq++) {
            float4 xa = *(const float4*)(xrow + kq * 32);
            float4 xb = *(const float4*)(xrow + kq * 32 + 4);
            union { short8 s; u32 u[4]; } tc;
            tc.u[0] = pk_bf16_up(xa.x, xa.y);
            tc.u[1] = pk_bf16_up(xa.z, xa.w);
            tc.u[2] = pk_bf16_up(xb.x, xb.y);
            tc.u[3] = pk_bf16_up(xb.z, xb.w);
            af[kq] = tc.s;
        }
    }

    const u16* wfl = wf + (size_t)ln * 8;   // lane base; frag stride 512 u16

    // output addressing (precomputed once)
    size_t base_i[4];
    size_t vbase = 0; int vkk = 0;
    if (which == 0) {
        #pragma unroll
        for (int i = 0; i < 4; i++) {
            int m  = r0 + quad * 4 + i;
            int b  = m / 500;
            int l0 = m - 500 * b;
            base_i[i] = (size_t)(b * 2000 + l0) * 64 + n16;
        }
    } else {
        int m0  = r0 + quad * 4;             // 4-aligned; never straddles b
        int b   = m0 / 500;
        int l00 = m0 - 500 * b;
        int vc  = l00 >> 6; vkk = l00 & 63;
        vbase = (size_t)b * 131072 + (size_t)vc * 4096;
    }

    // store helper (branch is wave-uniform)
    auto store_tile = [&](int tn, const f32x4& c) {
        if (which == 0) {
            size_t hoff = (size_t)(tn >> 2) * 32000 + (tn & 3) * 16;
            #pragma unroll
            for (int i = 0; i < 4; i++)
                qh_bf[base_i[i] + hoff] = f2bf(c[i]);
        } else {
            int d = (tn & 3) * 16 + n16;
            __align__(8) u16 t4[4];
            #pragma unroll
            for (int i = 0; i < 4; i++) t4[i] = f2bf(c[i]);
            *(uint2*)&vhT[vbase + (size_t)(tn >> 2) * 32768 + d * 64 +
                          (vkk ^ ((d & 7) << 3))] = *(const uint2*)t4;
        }
    };

    // ---- software-pipelined tile loop: compute(bA) overlaps load(bB) ----
    short8 bA[8], bB[8];
    #pragma unroll
    for (int kq = 0; kq < 8; kq++)
        bA[kq] = *(const short8*)(wfl + (size_t)(kq * 16 + 0) * 512);

    #pragma unroll
    for (int tp = 0; tp < 8; tp++) {
        const int tn0 = tp * 2, tn1 = tp * 2 + 1;
        // issue loads for tile tn1 (independent of bA's MFMA chain)
        #pragma unroll
        for (int kq = 0; kq < 8; kq++)
            bB[kq] = *(const short8*)(wfl + (size_t)(kq * 16 + tn1) * 512);
        // compute tile tn0 from bA
        {
            f32x4 c = {0.f, 0.f, 0.f, 0.f};
            #pragma unroll
            for (int kq = 0; kq < 8; kq++)
                c = __builtin_amdgcn_mfma_f32_16x16x32_bf16(af[kq], bA[kq], c, 0, 0, 0);
            store_tile(tn0, c);
        }
        // issue loads for tile tn0+2 (next pair's even tile) into bA
        if (tp < 7) {
            #pragma unroll
            for (int kq = 0; kq < 8; kq++)
                bA[kq] = *(const short8*)(wfl + (size_t)(kq * 16 + tn0 + 2) * 512);
        }
        // compute tile tn1 from bB
        {
            f32x4 c = {0.f, 0.f, 0.f, 0.f};
            #pragma unroll
            for (int kq = 0; kq < 8; kq++)
                c = __builtin_amdgcn_mfma_f32_16x16x32_bf16(af[kq], bB[kq], c, 0, 0, 0);
            store_tile(tn1, c);
        }
    }
}

// ---------------------------------------------------------------------------
// Kernel 2: dense-synthesizer attention — LDS-bandwidth-optimized, 1 pass.
// grid (256) = 1 block/bh/CU; block 512 = 8 waves x 64 rows (4 rgs of 16).
// B-fragments (w2, V, bias) feed FOUR MFMAs per read; 8 chunk-steps total.
// LDS: w2 64KB + V dbuf 16KB + b2 2KB + scr 72KB = 157.7KB (1 block/CU).
// ---------------------------------------------------------------------------
__global__ __launch_bounds__(512, 1) void attn_kernel(
    const u16* __restrict__ qh, const u16* __restrict__ vhT,
    const u16* __restrict__ w1T, const float* __restrict__ b1,
    const u16* __restrict__ w2sw, const float* __restrict__ b2p,
    u16* __restrict__ ctx)
{
    __shared__ __align__(16) u16 w2all[32768];       // [cc][row][k^swz], 64KB
    __shared__ __align__(16) u16 v_s[2][4096];       // [buf][d*64 + k^swz], 16KB
    __shared__ __align__(16) float b2s[512];         // scaled bias, 2KB
    __shared__ __align__(16) u16 scr[8][4][16][72];  // per-wave/rg s,P scratch

    const int tid  = threadIdx.x;
    const int wv   = tid >> 6;       // 0..7
    const int ln   = tid & 63;
    const int n16  = ln & 15;
    const int quad = ln >> 4;
    const int bh   = blockIdx.x;
    const int r0   = wv * 64;        // wave's 64 rows

    const u16* vg = vhT + (size_t)bh * 32768;

    // ---- one-shot staging: all of w2 (8 DMA/wave), v[0], b2 ----
    {
        int base = wv * 4096;
        #pragma unroll
        for (int j = 0; j < 8; j++)
            gload_lds16(w2sw + base + j * 512 + ln * 8, &w2all[base + j * 512]);
        gload_lds16(vg + wv * 512 + ln * 8, &v_s[0][wv * 512]);
        if (wv < 2)
            gload_lds16((const u16*)b2p + wv * 512 + ln * 8, (u16*)&b2s[wv * 256]);
    }

    const int b = bh >> 2, h = bh & 3;

    // ---- Phase A (swapped): s = relu(qh @ w1 + b1) -> packed scr, 4 rgs ----
    {
        short8 a0[4], a1[4];
        #pragma unroll
        for (int rg = 0; rg < 4; rg++) {
            const u16* qbase =
                qh + ((size_t)(bh * 500 + r0 + rg * 16 + n16)) * 64;
            a0[rg] = *(const short8*)(qbase + quad * 8);
            a1[rg] = *(const short8*)(qbase + 32 + quad * 8);
        }
        #pragma unroll
        for (int nt = 0; nt < 4; nt++) {
            const u16* wb = w1T + (nt * 16 + n16) * 64;
            short8 wA0 = *(const short8*)(wb + quad * 8);
            short8 wA1 = *(const short8*)(wb + 32 + quad * 8);
            float4 bv = *(const float4*)&b1[nt * 16 + quad * 4];
            #pragma unroll
            for (int rg = 0; rg < 4; rg++) {
                f32x4 c = {bv.x, bv.y, bv.z, bv.w};
                c = __builtin_amdgcn_mfma_f32_16x16x32_bf16(wA0, a0[rg], c, 0, 0, 0);
                c = __builtin_amdgcn_mfma_f32_16x16x32_bf16(wA1, a1[rg], c, 0, 0, 0);
                u32 p01 = pk_bf16_up(fmaxf(c[0], 0.f), fmaxf(c[1], 0.f));
                u32 p23 = pk_bf16_up(fmaxf(c[2], 0.f), fmaxf(c[3], 0.f));
                *(uint2*)&scr[wv][rg][n16][nt * 16 + quad * 4] =
                    make_uint2(p01, p23);
            }
        }
    }
    short8 sa0[4], sa1[4];
    #pragma unroll
    for (int rg = 0; rg < 4; rg++) {
        sa0[rg] = *(const short8*)&scr[wv][rg][n16][quad * 8];
        sa1[rg] = *(const short8*)&scr[wv][rg][n16][32 + quad * 8];
    }

    f32x4 oacc[4][4];
    #pragma unroll
    for (int rg = 0; rg < 4; rg++)
        #pragma unroll
        for (int nt = 0; nt < 4; nt++)
            oacc[rg][nt] = (f32x4){0.f, 0.f, 0.f, 0.f};
    float sm[4] = {0.f, 0.f, 0.f, 0.f};

    __syncthreads();   // prologue staging complete

    // ---- main: 8 chunks; B-frags shared across 4 rgs ----
    #pragma unroll 2
    for (int cc = 0; cc < 8; cc++) {
        if (cc < 7)
            gload_lds16(vg + (cc + 1) * 4096 + wv * 512 + ln * 8,
                        &v_s[(cc + 1) & 1][wv * 512]);
        const u16* vbuf = &v_s[cc & 1][0];

        // logits (swapped) + exp2 + pack -> scr, per t-tile
        #pragma unroll
        for (int t = 0; t < 4; t++) {
            int r  = t * 16 + n16;
            int sw = (r & 7) << 3;
            const u16* wb = &w2all[cc * 4096 + r * 64];
            short8 wA0 = *(const short8*)&wb[(quad * 8) ^ sw];
            short8 wA1 = *(const short8*)&wb[(32 + quad * 8) ^ sw];
            float4 bv = *(const float4*)&b2s[cc * 64 + t * 16 + quad * 4];
            #pragma unroll
            for (int rg = 0; rg < 4; rg++) {
                f32x4 c = {bv.x, bv.y, bv.z, bv.w};
                c = __builtin_amdgcn_mfma_f32_16x16x32_bf16(wA0, sa0[rg], c, 0, 0, 0);
                c = __builtin_amdgcn_mfma_f32_16x16x32_bf16(wA1, sa1[rg], c, 0, 0, 0);
                float e0 = exp2_fast(c[0]);
                float e1 = exp2_fast(c[1]);
                float e2 = exp2_fast(c[2]);
                float e3 = exp2_fast(c[3]);
                sm[rg] += (e0 + e1) + (e2 + e3);
                *(uint2*)&scr[wv][rg][n16][t * 16 + quad * 4] =
                    make_uint2(pk_bf16_up(e0, e1), pk_bf16_up(e2, e3));
            }
        }
        // PV: V-frag read once, feeds all 4 rgs
        #pragma unroll
        for (int ks = 0; ks < 2; ks++) {
            short8 pa[4];
            #pragma unroll
            for (int rg = 0; rg < 4; rg++)
                pa[rg] = *(const short8*)&scr[wv][rg][n16][ks * 32 + quad * 8];
            #pragma unroll
            for (int nt = 0; nt < 4; nt++) {
                int d   = nt * 16 + n16;
                int swd = (d & 7) << 3;
                short8 vb = *(const short8*)&vbuf[d * 64 +
                                                  ((ks * 32 + quad * 8) ^ swd)];
                #pragma unroll
                for (int rg = 0; rg < 4; rg++)
                    oacc[rg][nt] = __builtin_amdgcn_mfma_f32_16x16x32_bf16(
                        pa[rg], vb, oacc[rg][nt], 0, 0, 0);
            }
        }
        __syncthreads();   // next V staged; buffer safe to flip
    }

    // ---- epilogue: row-sum reduce + scaled bf16 store ----
    #pragma unroll
    for (int rg = 0; rg < 4; rg++) {
        float smt = sm[rg];
        smt += __shfl_xor(smt, 16);
        smt += __shfl_xor(smt, 32);   // lane now holds total for row n16
        #pragma unroll
        for (int i = 0; i < 4; i++) {
            int lrow = r0 + rg * 16 + quad * 4 + i;
            float si = __shfl(smt, quad * 4 + i);   // row (quad*4+i)'s sum
            if (lrow < 500) {
                float s = 1.f / si;
                u16* dst = &ctx[((size_t)(b * 500 + lrow)) * 256 + h * 64];
                #pragma unroll
                for (int nt = 0; nt < 4; nt++)
                    dst[nt * 16 + n16] = f2bf(oacc[rg][nt][i] * s);
            }
        }
    }
}

// ---------------------------------------------------------------------------
// Kernel 3: out = LayerNorm(ctx @ fc_w + q), bf16 MFMA + fused LN epilogue.
// grid (500), block 512 = 8 waves in 2x4; block tile 64 rows x 256 cols.
// ---------------------------------------------------------------------------
__global__ __launch_bounds__(512) void final_kernel(
    const u16* __restrict__ ctx, const u16* __restrict__ fcwT,
    const float* __restrict__ qres, const float* __restrict__ g,
    const float* __restrict__ bta, float* __restrict__ out)
{
    __shared__ u16 Xs[64][72];
    __shared__ u16 Ws[256][72];
    __shared__ float red[4][2][64];   // [wc][s1|s2][row]
    __shared__ float murs[2][64];     // [mu|rs][row]

    const int tid  = threadIdx.x;
    const int wvid = tid >> 6, ln = tid & 63;
    const int n16  = ln & 15, quad = ln >> 4;
    const int wr   = wvid >> 2, wc = wvid & 3;   // 2 x 4
    const int row0 = blockIdx.x * 64;

    f32x4 acc[2][4];
    #pragma unroll
    for (int mt = 0; mt < 2; mt++)
        #pragma unroll
        for (int nt = 0; nt < 4; nt++) acc[mt][nt] = (f32x4){0.f, 0.f, 0.f, 0.f};

    for (int kc = 0; kc < 256; kc += 64) {
        // stage X: 64 x 64 bf16
        {
            int idx = tid;
            int m = idx >> 3, k8 = idx & 7;
            *(uint4*)&Xs[m][k8 * 8] =
                *(const uint4*)&ctx[(size_t)(row0 + m) * 256 + kc + k8 * 8];
        }
        // stage W^T: 256 x 64 bf16
        #pragma unroll
        for (int j = 0; j < 4; j++) {
            int idx = tid + 512 * j;
            int n = idx >> 3, k8 = idx & 7;
            *(uint4*)&Ws[n][k8 * 8] = *(const uint4*)&fcwT[n * 256 + kc + k8 * 8];
        }
        __syncthreads();
        #pragma unroll
        for (int ks = 0; ks < 2; ks++) {
            short8 af[2], bfr[4];
            #pragma unroll
            for (int mt = 0; mt < 2; mt++)
                af[mt] = *(const short8*)&Xs[wr * 32 + mt * 16 + n16][ks * 32 + quad * 8];
            #pragma unroll
            for (int nt = 0; nt < 4; nt++)
                bfr[nt] = *(const short8*)&Ws[wc * 64 + nt * 16 + n16][ks * 32 + quad * 8];
            #pragma unroll
            for (int mt = 0; mt < 2; mt++)
                #pragma unroll
                for (int nt = 0; nt < 4; nt++)
                    acc[mt][nt] = __builtin_amdgcn_mfma_f32_16x16x32_bf16(
                        af[mt], bfr[nt], acc[mt][nt], 0, 0, 0);
        }
        __syncthreads();
    }

    // residual add
    #pragma unroll
    for (int mt = 0; mt < 2; mt++) {
        int m0 = row0 + wr * 32 + mt * 16 + quad * 4;
        #pragma unroll
        for (int i = 0; i < 4; i++) {
            const float* rp = &qres[(size_t)(m0 + i) * 256 + wc * 64 + n16];
            #pragma unroll
            for (int nt = 0; nt < 4; nt++)
                acc[mt][nt][i] += rp[nt * 16];
        }
    }
    // per-row partial sums -> LDS
    #pragma unroll
    for (int mt = 0; mt < 2; mt++) {
        #pragma unroll
        for (int i = 0; i < 4; i++) {
            float s1 = 0.f, s2 = 0.f;
            #pragma unroll
            for (int nt = 0; nt < 4; nt++) {
                float vv = acc[mt][nt][i];
                s1 += vv; s2 += vv * vv;
            }
            #pragma unroll
            for (int off = 1; off < 16; off <<= 1) {
                s1 += __shfl_xor(s1, off);
                s2 += __shfl_xor(s2, off);
            }
            if (n16 == 0) {
                int r = wr * 32 + mt * 16 + quad * 4 + i;
                red[wc][0][r] = s1;
                red[wc][1][r] = s2;
            }
        }
    }
    __syncthreads();
    if (tid < 64) {
        float S1 = red[0][0][tid] + red[1][0][tid] + red[2][0][tid] + red[3][0][tid];
        float S2 = red[0][1][tid] + red[1][1][tid] + red[2][1][tid] + red[3][1][tid];
        float mu  = S1 * 0.00390625f;
        float var = S2 * 0.00390625f - mu * mu;
        murs[0][tid] = mu;
        murs[1][tid] = rsqrtf(var + 1e-6f);
    }
    __syncthreads();

    float gv[4], bv[4];
    #pragma unroll
    for (int nt = 0; nt < 4; nt++) {
        int col = wc * 64 + nt * 16 + n16;
        gv[nt] = g[col];
        bv[nt] = bta[col];
    }
    #pragma unroll
    for (int mt = 0; mt < 2; mt++) {
        int rb = wr * 32 + mt * 16 + quad * 4;
        #pragma unroll
        for (int i = 0; i < 4; i++) {
            float mu = murs[0][rb + i];
            float rs = murs[1][rb + i];
            float* op = &out[(size_t)(row0 + rb + i) * 256 + wc * 64 + n16];
            #pragma unroll
            for (int nt = 0; nt < 4; nt++)
                op[nt * 16] = (acc[mt][nt][i] - mu) * rs * gv[nt] + bv[nt];
        }
    }
}

// ---------------------------------------------------------------------------
extern "C" void kernel_launch(void* const* d_in, const int* in_sizes, int n_in,
                              void* d_out, int out_size, void* d_ws, size_t ws_size,
                              hipStream_t stream)
{
    const float* q   = (const float*)d_in[0];
    const float* v   = (const float*)d_in[2];
    const float* wqs = (const float*)d_in[3];
    const float* wvs = (const float*)d_in[4];
    const float* w1  = (const float*)d_in[5];
    const float* b1  = (const float*)d_in[6];
    const float* w2  = (const float*)d_in[7];
    const float* b2  = (const float*)d_in[8];
    const float* fcw = (const float*)d_in[9];
    const float* lng = (const float*)d_in[10];
    const float* lnb = (const float*)d_in[11];
    float* out = (float*)d_out;

    u16* qh_bf = (u16*)d_ws;            // 8,200,192 (rows >=500*256 are pad)
    u16* vhT   = qh_bf + 8200192;       // 8,388,608 (chunk-tiled + swizzled)
    u16* w1T   = vhT + 8388608;         // 4,096
    u16* w2sw  = w1T + 4096;            // 32,768 (chunk-tiled + swizzled + log2e)
    u16* wqf   = w2sw + 32768;          // 65,536 (MFMA-fragment layout)
    u16* wvf   = wqf + 65536;           // 65,536 (MFMA-fragment layout)
    u16* fcwT  = wvf + 65536;           // 65,536
    u16* ctx   = fcwT + 65536;          // 8,192,000
    float* b2p = (float*)(qh_bf + 8195072);  // 512 floats inside qh_bf tail pad

    prep_kernel <<<dim3(64),     256, 0, stream>>>(wqs, wvs, fcw, w1, w2, b2,
                                                   wqf, wvf, fcwT, w1T, w2sw,
                                                   qh_bf, vhT, b2p);
    proj_kernel <<<dim3(1000),   256, 0, stream>>>(q, v, wqf, wvf, qh_bf, vhT);
    attn_kernel <<<dim3(256),    512, 0, stream>>>(qh_bf, vhT, w1T, b1, w2sw, b2p, ctx);
    final_kernel<<<dim3(500),    512, 0, stream>>>(ctx, fcwT, q, lng, lnb, out);
}

// Round 18
// 83.527 us; speedup vs baseline: 1.1965x; 1.0799x over previous
//
#include <hip/hip_runtime.h>
#include <math.h>

#define B_   64
#define L_   500
#define F_   256
#define H_   4
#define DK   64
#define LOG2E 1.44269504088896340736f

typedef unsigned short u16;
typedef unsigned int   u32;
typedef __attribute__((ext_vector_type(8))) short short8;
typedef __attribute__((ext_vector_type(4))) float f32x4;

static __device__ __forceinline__ u16 f2bf(float f) {
    u32 u = __float_as_uint(f);
    u32 r = (u + 0x7FFFu + ((u >> 16) & 1u)) >> 16;
    return (u16)r;
}
// pack two floats to 2x bf16 (round-half-up) in one u32: {hi=y, lo=x}
static __device__ __forceinline__ u32 pk_bf16_up(float x, float y) {
    u32 xb = __float_as_uint(x) + 0x8000u;
    u32 yb = __float_as_uint(y) + 0x8000u;
    return (xb >> 16) | (yb & 0xFFFF0000u);
}
static __device__ __forceinline__ float exp2_fast(float x) {
#if __has_builtin(__builtin_amdgcn_exp2f)
    return __builtin_amdgcn_exp2f(x);
#else
    return exp2f(x);
#endif
}

typedef __attribute__((address_space(3))) u32 lds32;
typedef const __attribute__((address_space(1))) u32 gbl32;
// async global->LDS DMA, 16 B/lane, LDS dest = uniform base + lane*16
static __device__ __forceinline__ void gload_lds16(const u16* g, u16* l) {
    __builtin_amdgcn_global_load_lds((gbl32*)g, (lds32*)l, 16, 0, 0);
}

// ---------------------------------------------------------------------------
// Prep: bf16 transposed weights + padded b2 + pad-zeroing of ws regions.
//  wqT/wvT/fcwT [256][256] ([n][k]); w1T[64][64]
//  w2sw: chunk-tiled + XOR-swizzled + PRE-SCALED by log2(e):
//        w2sw[cc][row][k] = log2e * w2[k ^ ((row&7)<<3)][cc*64+row]
//  b2p[512] float = log2e * b2 (tail -1e30 -> exp2() == 0)
// ---------------------------------------------------------------------------
__global__ __launch_bounds__(256) void prep_kernel(
    const float* __restrict__ wq, const float* __restrict__ wv,
    const float* __restrict__ fcw, const float* __restrict__ w1,
    const float* __restrict__ w2, const float* __restrict__ b2,
    u16* __restrict__ wqT, u16* __restrict__ wvT, u16* __restrict__ fcwT,
    u16* __restrict__ w1T, u16* __restrict__ w2sw,
    u16* __restrict__ qh_bf, u16* __restrict__ vhT, float* __restrict__ b2p)
{
    int t = blockIdx.x * 256 + threadIdx.x;
    int stride = gridDim.x * 256;                 // 16384
    for (int i = t; i < 256 * 256; i += stride) {
        int n = i >> 8, k = i & 255;
        wqT[i]  = f2bf(wq[k * 256 + n]);
        wvT[i]  = f2bf(wv[k * 256 + n]);
        fcwT[i] = f2bf(fcw[k * 256 + n]);
    }
    for (int i = t; i < 64 * 64; i += stride) {
        int n = i >> 6, k = i & 63;
        w1T[i] = f2bf(w1[k * 64 + n]);
    }
    // w2 chunk-tiled + swizzled + log2e-scaled
    for (int i = t; i < 512 * 64; i += stride) {
        int cc  = i >> 12;
        int row = (i >> 6) & 63;
        int kc  = i & 63;
        int n   = cc * 64 + row;
        int kl  = kc ^ ((row & 7) << 3);
        w2sw[i] = f2bf((n < 500 ? w2[kl * 500 + n] : 0.f) * LOG2E);
    }
    // padded, scaled bias (tail -> exp2() == 0)
    for (int i = t; i < 512; i += stride)
        b2p[i] = (i < 500) ? b2[i] * LOG2E : -1e30f;
    // zero qh_bf pad rows read by attn (rows >= 128000); b2p lives at 8195072+
    for (int i = t; i < 3072; i += stride)
        qh_bf[8192000 + i] = 0;
    // zero vhT swizzled pad slots: chunk 7, k 52..63 for every (bh, d)
    for (int i = t; i < 196608; i += stride) {
        int bh = i / 768;
        int r  = i - bh * 768;
        int d  = r / 12;
        int kk = 52 + (r - d * 12);
        vhT[((size_t)((bh * 8 + 7) * 64 + d)) * 64 + (kk ^ ((d & 7) << 3))] = 0;
    }
}

// ---------------------------------------------------------------------------
// Kernel 1: head projections, bf16 MFMA.
// grid (500, 2), block 512 = 8 waves in 2x4; block tile 64 rows x 256 cols.
// which=0: qh_bf [bh][500][64]
// which=1: vhT chunk-tiled+swizzled [bh][cc=8][d=64][k=64],
//          vhT[bh][cc][d][k ^ ((d&7)<<3)] = v_head[bh][d][cc*64+k]
// ---------------------------------------------------------------------------
__global__ __launch_bounds__(512) void proj_kernel(
    const float* __restrict__ q, const float* __restrict__ v,
    const u16* __restrict__ wqT, const u16* __restrict__ wvT,
    u16* __restrict__ qh_bf, u16* __restrict__ vhT)
{
    const int which = blockIdx.y;
    const float* __restrict__ x = which ? v : q;
    const u16*   __restrict__ wT = which ? wvT : wqT;

    __shared__ u16 Xs[64][72];    // [m][k], pad 144 B
    __shared__ u16 Ws[256][72];   // [n][k], pad 144 B

    const int tid  = threadIdx.x;
    const int wvid = tid >> 6, ln = tid & 63;
    const int n16  = ln & 15, quad = ln >> 4;
    const int wr   = wvid >> 2, wc = wvid & 3;   // 2 x 4
    const int row0 = blockIdx.x * 64;

    f32x4 acc[2][4];
    #pragma unroll
    for (int mt = 0; mt < 2; mt++)
        #pragma unroll
        for (int nt = 0; nt < 4; nt++) acc[mt][nt] = (f32x4){0.f, 0.f, 0.f, 0.f};

    for (int kc = 0; kc < 256; kc += 64) {
        // stage X (fp32 -> bf16): 64 x 64
        #pragma unroll
        for (int j = 0; j < 2; j++) {
            int idx = tid + 512 * j;
            int m = idx >> 4, k4 = idx & 15;
            float4 a = *(const float4*)&x[(size_t)(row0 + m) * 256 + kc + k4 * 4];
            __align__(8) u16 t4[4] = {f2bf(a.x), f2bf(a.y), f2bf(a.z), f2bf(a.w)};
            *(uint2*)&Xs[m][k4 * 4] = *(const uint2*)t4;
        }
        // stage W^T: 256 x 64 bf16
        #pragma unroll
        for (int j = 0; j < 4; j++) {
            int idx = tid + 512 * j;
            int n = idx >> 3, k8 = idx & 7;
            *(uint4*)&Ws[n][k8 * 8] = *(const uint4*)&wT[n * 256 + kc + k8 * 8];
        }
        __syncthreads();
        #pragma unroll
        for (int ks = 0; ks < 2; ks++) {
            short8 af[2], bfr[4];
            #pragma unroll
            for (int mt = 0; mt < 2; mt++)
                af[mt] = *(const short8*)&Xs[wr * 32 + mt * 16 + n16][ks * 32 + quad * 8];
            #pragma unroll
            for (int nt = 0; nt < 4; nt++)
                bfr[nt] = *(const short8*)&Ws[wc * 64 + nt * 16 + n16][ks * 32 + quad * 8];
            #pragma unroll
            for (int mt = 0; mt < 2; mt++)
                #pragma unroll
                for (int nt = 0; nt < 4; nt++)
                    acc[mt][nt] = __builtin_amdgcn_mfma_f32_16x16x32_bf16(
                        af[mt], bfr[nt], acc[mt][nt], 0, 0, 0);
        }
        __syncthreads();
    }

    // h = wc (64-col groups), d = nt*16 + n16
    if (which == 0) {
        #pragma unroll
        for (int mt = 0; mt < 2; mt++) {
            int m0 = row0 + wr * 32 + mt * 16 + quad * 4;   // mult of 4
            int b  = m0 / 500;
            int l0 = m0 - 500 * b;                           // group never straddles b
            #pragma unroll
            for (int nt = 0; nt < 4; nt++) {
                int d = nt * 16 + n16;
                u16* dst = qh_bf + ((size_t)((b * 4 + wc) * 500 + l0)) * 64 + d;
                #pragma unroll
                for (int i = 0; i < 4; i++)
                    dst[(size_t)i * 64] = f2bf(acc[mt][nt][i]);
            }
        }
    } else {
        #pragma unroll
        for (int mt = 0; mt < 2; mt++) {
            int m0 = row0 + wr * 32 + mt * 16 + quad * 4;
            int b  = m0 / 500;
            int l0 = m0 - 500 * b;                           // 4-aligned
            int cc = l0 >> 6, kk = l0 & 63;
            #pragma unroll
            for (int nt = 0; nt < 4; nt++) {
                int d = nt * 16 + n16;
                __align__(8) u16 t4[4];
                #pragma unroll
                for (int i = 0; i < 4; i++) t4[i] = f2bf(acc[mt][nt][i]);
                size_t base = ((size_t)(((b * 4 + wc) * 8 + cc) * 64 + d)) * 64;
                *(uint2*)&vhT[base + (kk ^ ((d & 7) << 3))] = *(const uint2*)t4;
            }
        }
    }
}

// ---------------------------------------------------------------------------
// Kernel 2: dense-synthesizer attention — LDS-bandwidth-optimized, 1 pass.
// grid (256) = 1 block/bh/CU; block 512 = 8 waves x 64 rows (4 rgs of 16).
// B-fragments (w2, V, bias) feed FOUR MFMAs per read; 8 chunk-steps total.
// LDS: w2 64KB + V dbuf 16KB + b2 2KB + scr 72KB = 157.7KB (1 block/CU).
// ---------------------------------------------------------------------------
__global__ __launch_bounds__(512, 1) void attn_kernel(
    const u16* __restrict__ qh, const u16* __restrict__ vhT,
    const u16* __restrict__ w1T, const float* __restrict__ b1,
    const u16* __restrict__ w2sw, const float* __restrict__ b2p,
    u16* __restrict__ ctx)
{
    __shared__ __align__(16) u16 w2all[32768];       // [cc][row][k^swz], 64KB
    __shared__ __align__(16) u16 v_s[2][4096];       // [buf][d*64 + k^swz], 16KB
    __shared__ __align__(16) float b2s[512];         // scaled bias, 2KB
    __shared__ __align__(16) u16 scr[8][4][16][72];  // per-wave/rg s,P scratch

    const int tid  = threadIdx.x;
    const int wv   = tid >> 6;       // 0..7
    const int ln   = tid & 63;
    const int n16  = ln & 15;
    const int quad = ln >> 4;
    const int bh   = blockIdx.x;
    const int r0   = wv * 64;        // wave's 64 rows

    const u16* vg = vhT + (size_t)bh * 32768;

    // ---- one-shot staging: all of w2 (8 DMA/wave), v[0], b2 ----
    {
        int base = wv * 4096;
        #pragma unroll
        for (int j = 0; j < 8; j++)
            gload_lds16(w2sw + base + j * 512 + ln * 8, &w2all[base + j * 512]);
        gload_lds16(vg + wv * 512 + ln * 8, &v_s[0][wv * 512]);
        if (wv < 2)
            gload_lds16((const u16*)b2p + wv * 512 + ln * 8, (u16*)&b2s[wv * 256]);
    }

    const int b = bh >> 2, h = bh & 3;

    // ---- Phase A (swapped): s = relu(qh @ w1 + b1) -> packed scr, 4 rgs ----
    {
        short8 a0[4], a1[4];
        #pragma unroll
        for (int rg = 0; rg < 4; rg++) {
            const u16* qbase =
                qh + ((size_t)(bh * 500 + r0 + rg * 16 + n16)) * 64;
            a0[rg] = *(const short8*)(qbase + quad * 8);
            a1[rg] = *(const short8*)(qbase + 32 + quad * 8);
        }
        #pragma unroll
        for (int nt = 0; nt < 4; nt++) {
            const u16* wb = w1T + (nt * 16 + n16) * 64;
            short8 wA0 = *(const short8*)(wb + quad * 8);
            short8 wA1 = *(const short8*)(wb + 32 + quad * 8);
            float4 bv = *(const float4*)&b1[nt * 16 + quad * 4];
            #pragma unroll
            for (int rg = 0; rg < 4; rg++) {
                f32x4 c = {bv.x, bv.y, bv.z, bv.w};
                c = __builtin_amdgcn_mfma_f32_16x16x32_bf16(wA0, a0[rg], c, 0, 0, 0);
                c = __builtin_amdgcn_mfma_f32_16x16x32_bf16(wA1, a1[rg], c, 0, 0, 0);
                u32 p01 = pk_bf16_up(fmaxf(c[0], 0.f), fmaxf(c[1], 0.f));
                u32 p23 = pk_bf16_up(fmaxf(c[2], 0.f), fmaxf(c[3], 0.f));
                *(uint2*)&scr[wv][rg][n16][nt * 16 + quad * 4] =
                    make_uint2(p01, p23);
            }
        }
    }
    short8 sa0[4], sa1[4];
    #pragma unroll
    for (int rg = 0; rg < 4; rg++) {
        sa0[rg] = *(const short8*)&scr[wv][rg][n16][quad * 8];
        sa1[rg] = *(const short8*)&scr[wv][rg][n16][32 + quad * 8];
    }

    f32x4 oacc[4][4];
    #pragma unroll
    for (int rg = 0; rg < 4; rg++)
        #pragma unroll
        for (int nt = 0; nt < 4; nt++)
            oacc[rg][nt] = (f32x4){0.f, 0.f, 0.f, 0.f};
    float sm[4] = {0.f, 0.f, 0.f, 0.f};

    __syncthreads();   // prologue staging complete

    // ---- main: 8 chunks; B-frags shared across 4 rgs ----
    #pragma unroll 2
    for (int cc = 0; cc < 8; cc++) {
        if (cc < 7)
            gload_lds16(vg + (cc + 1) * 4096 + wv * 512 + ln * 8,
                        &v_s[(cc + 1) & 1][wv * 512]);
        const u16* vbuf = &v_s[cc & 1][0];

        // logits (swapped) + exp2 + pack -> scr, per t-tile
        #pragma unroll
        for (int t = 0; t < 4; t++) {
            int r  = t * 16 + n16;
            int sw = (r & 7) << 3;
            const u16* wb = &w2all[cc * 4096 + r * 64];
            short8 wA0 = *(const short8*)&wb[(quad * 8) ^ sw];
            short8 wA1 = *(const short8*)&wb[(32 + quad * 8) ^ sw];
            float4 bv = *(const float4*)&b2s[cc * 64 + t * 16 + quad * 4];
            #pragma unroll
            for (int rg = 0; rg < 4; rg++) {
                f32x4 c = {bv.x, bv.y, bv.z, bv.w};
                c = __builtin_amdgcn_mfma_f32_16x16x32_bf16(wA0, sa0[rg], c, 0, 0, 0);
                c = __builtin_amdgcn_mfma_f32_16x16x32_bf16(wA1, sa1[rg], c, 0, 0, 0);
                float e0 = exp2_fast(c[0]);
                float e1 = exp2_fast(c[1]);
                float e2 = exp2_fast(c[2]);
                float e3 = exp2_fast(c[3]);
                sm[rg] += (e0 + e1) + (e2 + e3);
                *(uint2*)&scr[wv][rg][n16][t * 16 + quad * 4] =
                    make_uint2(pk_bf16_up(e0, e1), pk_bf16_up(e2, e3));
            }
        }
        // PV: V-frag read once, feeds all 4 rgs
        #pragma unroll
        for (int ks = 0; ks < 2; ks++) {
            short8 pa[4];
            #pragma unroll
            for (int rg = 0; rg < 4; rg++)
                pa[rg] = *(const short8*)&scr[wv][rg][n16][ks * 32 + quad * 8];
            #pragma unroll
            for (int nt = 0; nt < 4; nt++) {
                int d   = nt * 16 + n16;
                int swd = (d & 7) << 3;
                short8 vb = *(const short8*)&vbuf[d * 64 +
                                                  ((ks * 32 + quad * 8) ^ swd)];
                #pragma unroll
                for (int rg = 0; rg < 4; rg++)
                    oacc[rg][nt] = __builtin_amdgcn_mfma_f32_16x16x32_bf16(
                        pa[rg], vb, oacc[rg][nt], 0, 0, 0);
            }
        }
        __syncthreads();   // next V staged; buffer safe to flip
    }

    // ---- epilogue: row-sum reduce + scaled bf16 store ----
    #pragma unroll
    for (int rg = 0; rg < 4; rg++) {
        float smt = sm[rg];
        smt += __shfl_xor(smt, 16);
        smt += __shfl_xor(smt, 32);   // lane now holds total for row n16
        #pragma unroll
        for (int i = 0; i < 4; i++) {
            int lrow = r0 + rg * 16 + quad * 4 + i;
            float si = __shfl(smt, quad * 4 + i);   // row (quad*4+i)'s sum
            if (lrow < 500) {
                float s = 1.f / si;
                u16* dst = &ctx[((size_t)(b * 500 + lrow)) * 256 + h * 64];
                #pragma unroll
                for (int nt = 0; nt < 4; nt++)
                    dst[nt * 16 + n16] = f2bf(oacc[rg][nt][i] * s);
            }
        }
    }
}

// ---------------------------------------------------------------------------
// Kernel 3: out = LayerNorm(ctx @ fc_w + q), bf16 MFMA + fused LN epilogue.
// grid (500), block 512 = 8 waves in 2x4; block tile 64 rows x 256 cols.
// ---------------------------------------------------------------------------
__global__ __launch_bounds__(512) void final_kernel(
    const u16* __restrict__ ctx, const u16* __restrict__ fcwT,
    const float* __restrict__ qres, const float* __restrict__ g,
    const float* __restrict__ bta, float* __restrict__ out)
{
    __shared__ u16 Xs[64][72];
    __shared__ u16 Ws[256][72];
    __shared__ float red[4][2][64];   // [wc][s1|s2][row]
    __shared__ float murs[2][64];     // [mu|rs][row]

    const int tid  = threadIdx.x;
    const int wvid = tid >> 6, ln = tid & 63;
    const int n16  = ln & 15, quad = ln >> 4;
    const int wr   = wvid >> 2, wc = wvid & 3;   // 2 x 4
    const int row0 = blockIdx.x * 64;

    f32x4 acc[2][4];
    #pragma unroll
    for (int mt = 0; mt < 2; mt++)
        #pragma unroll
        for (int nt = 0; nt < 4; nt++) acc[mt][nt] = (f32x4){0.f, 0.f, 0.f, 0.f};

    for (int kc = 0; kc < 256; kc += 64) {
        // stage X: 64 x 64 bf16
        {
            int idx = tid;
            int m = idx >> 3, k8 = idx & 7;
            *(uint4*)&Xs[m][k8 * 8] =
                *(const uint4*)&ctx[(size_t)(row0 + m) * 256 + kc + k8 * 8];
        }
        // stage W^T: 256 x 64 bf16
        #pragma unroll
        for (int j = 0; j < 4; j++) {
            int idx = tid + 512 * j;
            int n = idx >> 3, k8 = idx & 7;
            *(uint4*)&Ws[n][k8 * 8] = *(const uint4*)&fcwT[n * 256 + kc + k8 * 8];
        }
        __syncthreads();
        #pragma unroll
        for (int ks = 0; ks < 2; ks++) {
            short8 af[2], bfr[4];
            #pragma unroll
            for (int mt = 0; mt < 2; mt++)
                af[mt] = *(const short8*)&Xs[wr * 32 + mt * 16 + n16][ks * 32 + quad * 8];
            #pragma unroll
            for (int nt = 0; nt < 4; nt++)
                bfr[nt] = *(const short8*)&Ws[wc * 64 + nt * 16 + n16][ks * 32 + quad * 8];
            #pragma unroll
            for (int mt = 0; mt < 2; mt++)
                #pragma unroll
                for (int nt = 0; nt < 4; nt++)
                    acc[mt][nt] = __builtin_amdgcn_mfma_f32_16x16x32_bf16(
                        af[mt], bfr[nt], acc[mt][nt], 0, 0, 0);
        }
        __syncthreads();
    }

    // residual add
    #pragma unroll
    for (int mt = 0; mt < 2; mt++) {
        int m0 = row0 + wr * 32 + mt * 16 + quad * 4;
        #pragma unroll
        for (int i = 0; i < 4; i++) {
            const float* rp = &qres[(size_t)(m0 + i) * 256 + wc * 64 + n16];
            #pragma unroll
            for (int nt = 0; nt < 4; nt++)
                acc[mt][nt][i] += rp[nt * 16];
        }
    }
    // per-row partial sums -> LDS
    #pragma unroll
    for (int mt = 0; mt < 2; mt++) {
        #pragma unroll
        for (int i = 0; i < 4; i++) {
            float s1 = 0.f, s2 = 0.f;
            #pragma unroll
            for (int nt = 0; nt < 4; nt++) {
                float vv = acc[mt][nt][i];
                s1 += vv; s2 += vv * vv;
            }
            #pragma unroll
            for (int off = 1; off < 16; off <<= 1) {
                s1 += __shfl_xor(s1, off);
                s2 += __shfl_xor(s2, off);
            }
            if (n16 == 0) {
                int r = wr * 32 + mt * 16 + quad * 4 + i;
                red[wc][0][r] = s1;
                red[wc][1][r] = s2;
            }
        }
    }
    __syncthreads();
    if (tid < 64) {
        float S1 = red[0][0][tid] + red[1][0][tid] + red[2][0][tid] + red[3][0][tid];
        float S2 = red[0][1][tid] + red[1][1][tid] + red[2][1][tid] + red[3][1][tid];
        float mu  = S1 * 0.00390625f;
        float var = S2 * 0.00390625f - mu * mu;
        murs[0][tid] = mu;
        murs[1][tid] = rsqrtf(var + 1e-6f);
    }
    __syncthreads();

    float gv[4], bv[4];
    #pragma unroll
    for (int nt = 0; nt < 4; nt++) {
        int col = wc * 64 + nt * 16 + n16;
        gv[nt] = g[col];
        bv[nt] = bta[col];
    }
    #pragma unroll
    for (int mt = 0; mt < 2; mt++) {
        int rb = wr * 32 + mt * 16 + quad * 4;
        #pragma unroll
        for (int i = 0; i < 4; i++) {
            float mu = murs[0][rb + i];
            float rs = murs[1][rb + i];
            float* op = &out[(size_t)(row0 + rb + i) * 256 + wc * 64 + n16];
            #pragma unroll
            for (int nt = 0; nt < 4; nt++)
                op[nt * 16] = (acc[mt][nt][i] - mu) * rs * gv[nt] + bv[nt];
        }
    }
}

// ---------------------------------------------------------------------------
extern "C" void kernel_launch(void* const* d_in, const int* in_sizes, int n_in,
                              void* d_out, int out_size, void* d_ws, size_t ws_size,
                              hipStream_t stream)
{
    const float* q   = (const float*)d_in[0];
    const float* v   = (const float*)d_in[2];
    const float* wqs = (const float*)d_in[3];
    const float* wvs = (const float*)d_in[4];
    const float* w1  = (const float*)d_in[5];
    const float* b1  = (const float*)d_in[6];
    const float* w2  = (const float*)d_in[7];
    const float* b2  = (const float*)d_in[8];
    const float* fcw = (const float*)d_in[9];
    const float* lng = (const float*)d_in[10];
    const float* lnb = (const float*)d_in[11];
    float* out = (float*)d_out;

    u16* qh_bf = (u16*)d_ws;            // 8,200,192 (rows >=500*256 are pad)
    u16* vhT   = qh_bf + 8200192;       // 8,388,608 (chunk-tiled + swizzled)
    u16* w1T   = vhT + 8388608;         // 4,096
    u16* w2sw  = w1T + 4096;            // 32,768 (chunk-tiled + swizzled + log2e)
    u16* wqT   = w2sw + 32768;          // 65,536
    u16* wvT   = wqT + 65536;           // 65,536
    u16* fcwT  = wvT + 65536;           // 65,536
    u16* ctx   = fcwT + 65536;          // 8,192,000
    float* b2p = (float*)(qh_bf + 8195072);  // 512 floats inside qh_bf tail pad

    prep_kernel <<<dim3(64),     256, 0, stream>>>(wqs, wvs, fcw, w1, w2, b2,
                                                   wqT, wvT, fcwT, w1T, w2sw,
                                                   qh_bf, vhT, b2p);
    proj_kernel <<<dim3(500, 2), 512, 0, stream>>>(q, v, wqT, wvT, qh_bf, vhT);
    attn_kernel <<<dim3(256),    512, 0, stream>>>(qh_bf, vhT, w1T, b1, w2sw, b2p, ctx);
    final_kernel<<<dim3(500),    512, 0, stream>>>(ctx, fcwT, q, lng, lnb, out);
}